// Round 9
// baseline (446.350 us; speedup 1.0000x reference)
//
#include <hip/hip_runtime.h>

#define B_   32
#define HW_  196
#define C_   512
#define M_   (B_*HW_)    // 6272
#define HID_ 128
#define NBLK 18

typedef _Float16 f16;
typedef _Float16 f16x2 __attribute__((ext_vector_type(2)));
typedef _Float16 f16x4 __attribute__((ext_vector_type(4)));
typedef _Float16 f16x8 __attribute__((ext_vector_type(8)));
typedef float    f32x4 __attribute__((ext_vector_type(4)));

__device__ __forceinline__ float gelu_f(float x) {
    float t = tanhf(0.7978845608028654f * (x + 0.044715f * x * x * x));
    return 0.5f * x * (1.0f + t);
}

// async global->LDS, 16B per lane; LDS dest = wave-uniform base + lane*16
__device__ __forceinline__ void gl16(const void* g, void* l) {
    __builtin_amdgcn_global_load_lds((const __attribute__((address_space(1))) unsigned*)g,
                                     (__attribute__((address_space(3))) unsigned*)l, 16, 0, 0);
}

// ---------- weights: fp32 [blk][k][n] -> fp16 transposed [blk][n][k] ----------
__global__ __launch_bounds__(256) void conv_w(const float* __restrict__ W,
                                              f16* __restrict__ Wt) {
    __shared__ f16 sh[64][72];
    const int blk = blockIdx.z, k0 = blockIdx.x * 64, n0 = blockIdx.y * 64;
    const int tid = threadIdx.x;
    const float* Wb = W + (size_t)blk * C_ * C_;
    #pragma unroll
    for (int i = 0; i < 4; ++i) {
        int s = tid + i * 256, r = s >> 4, c4 = (s & 15) << 2;
        float4 v = *(const float4*)&Wb[(size_t)(k0 + r) * C_ + n0 + c4];
        sh[r][c4 + 0] = (f16)v.x; sh[r][c4 + 1] = (f16)v.y;
        sh[r][c4 + 2] = (f16)v.z; sh[r][c4 + 3] = (f16)v.w;
    }
    __syncthreads();
    #pragma unroll
    for (int i = 0; i < 2; ++i) {
        int s = tid + i * 256, r = s >> 3, c8 = (s & 7) << 3;
        f16x8 o;
        #pragma unroll
        for (int j = 0; j < 8; ++j) o[j] = sh[c8 + j][r];
        *(f16x8*)&Wt[(size_t)blk * C_ * C_ + (size_t)(n0 + r) * C_ + k0 + c8] = o;
    }
}

// ---------- x: fp32 -> fp16 (x4 vectorized); first 64 blocks also zero pooled ----------
__global__ __launch_bounds__(256) void conv_x(const float* __restrict__ in,
                                              f16* __restrict__ out,
                                              float* __restrict__ pooled) {
    int i = blockIdx.x * 256 + threadIdx.x;
    if (blockIdx.x < 64) pooled[i] = 0.f;   // 64*256 = 16384 = B_*C_
    float4 a = ((const float4*)in)[i];
    f16x4 o; o[0] = (f16)a.x; o[1] = (f16)a.y; o[2] = (f16)a.z; o[3] = (f16)a.w;
    ((f16x4*)out)[i] = o;
}

// ---------- MFMA GEMM: out = gelu(A[M,K]@W_blk[K,N] + b) [+ column-sum pooling] ----------
// 64x32x64 tile, 4 waves of 16x32 (acc 1x2). TLP is the binding constraint
// (r6/r8 curve: per-GEMM time monotone in resident blocks/CU: 1.5/CU=418us,
// 2/CU=472us*, 3.1/CU=385us) -> halve BN to double the grid: 1568 blocks =
// 6.1 blocks/CU = 24 waves/CU (LDS 24.25KB -> capacity 6; VGPR ~45 -> 6 w/SIMD).
// Same proven r6 skeleton: 2-buf drain loop, XOR-swizzled gl16 staging,
// bijective chunked-XCD swizzle (1568 = 8*196) for A-panel L2 locality.
#define BM 64
#define BN 32
#define BK 64
#define NKT (C_ / BK)   // 8
// LDS layout (halfs): tile[r][c-block] at r*64 + ((c ^ (r&7))<<3)
__global__ __launch_bounds__(256, 6) void gemm_f16(
    const f16* __restrict__ A, const f16* __restrict__ Wt,
    const float* __restrict__ ball, int blk, f16* __restrict__ out,
    float* __restrict__ pooled)
{
    __shared__ f16 As[2][BM * BK];   // 2 x 8 KB
    __shared__ f16 Ws[2][BN * BK];   // 2 x 4 KB  -> 24 KB total, 6 blocks/CU
    __shared__ float spool[2][BN];   // per-batch-slot column sums (256 B)
    const int tid = threadIdx.x;
    const int wave = tid >> 6, lane = tid & 63;
    const int m15 = lane & 15, q = lane >> 4;

    // chunked-XCD swizzle (bijective, 1568 = 8*196; 16 col-blocks = power of 2)
    const int lin  = blockIdx.x + 98 * blockIdx.y;     // hw dispatch order (grid 98x16)
    const int tile = (lin & 7) * 196 + (lin >> 3);     // contiguous chunk per XCD
    const int rb   = tile >> 4, cb = tile & 15;
    const int row0 = rb * BM, col0 = cb * BN;

    const f16* Wb = Wt + (size_t)blk * C_ * C_;
    const float* bias = ball + (size_t)blk * C_;

    // staging: chunk ch = 8 rows x 64k (1KB). lane l loads row ch*8+(l>>3),
    // col-block (l&7)^(srow&7), landing at LDS base+l*16 = swizzled layout.
    // A: 8 chunks (64 rows) -> 2 per wave; W: 4 chunks (32 rows) -> 1 per wave.
    const int srow = lane >> 3;
    const int scol = ((lane & 7) ^ (srow & 7)) << 3;   // halfs
    const f16* aSrc[2]; const f16* wSrc;
    f16* aDst[2][2]; f16* wDst[2];
    #pragma unroll
    for (int i = 0; i < 2; ++i) {
        int ch = wave * 2 + i;                          // 8 chunks cover 64 rows
        aSrc[i] = A + (size_t)(row0 + ch * 8 + srow) * C_ + scol;
        aDst[0][i] = &As[0][ch * 512]; aDst[1][i] = &As[1][ch * 512];
    }
    {
        wSrc = Wb + (size_t)(col0 + wave * 8 + srow) * C_ + scol;  // chunk = wave
        wDst[0] = &Ws[0][wave * 512]; wDst[1] = &Ws[1][wave * 512];
    }

    f32x4 acc[2];
    acc[0] = (f32x4)0.f; acc[1] = (f32x4)0.f;

    // prefetch tile 0 -> buf 0
    #pragma unroll
    for (int i = 0; i < 2; ++i) gl16(aSrc[i], aDst[0][i]);
    gl16(wSrc, wDst[0]);

    #pragma unroll
    for (int kt = 0; kt < NKT; ++kt) {
        __syncthreads();   // drains this tile's loads + syncs buffer reuse
        int cur = kt & 1;
        if (kt + 1 < NKT) {
            int nxt = cur ^ 1, koff = (kt + 1) * BK;
            #pragma unroll
            for (int i = 0; i < 2; ++i) gl16(aSrc[i] + koff, aDst[nxt][i]);
            gl16(wSrc + koff, wDst[nxt]);
        }
        const f16* Ab = &As[cur][0];
        const f16* Bb = &Ws[cur][0];
        #pragma unroll
        for (int kk = 0; kk < BK; kk += 32) {
            f16x8 af, bf[2];
            int c = (kk >> 3) + q;
            {
                int r = wave * 16 + m15;
                af = *(const f16x8*)&Ab[r * 64 + ((c ^ (r & 7)) << 3)];
            }
            #pragma unroll
            for (int j = 0; j < 2; ++j) {
                int r = j * 16 + m15;
                bf[j] = *(const f16x8*)&Bb[r * 64 + ((c ^ (r & 7)) << 3)];
            }
            __builtin_amdgcn_s_setprio(1);
            #pragma unroll
            for (int j = 0; j < 2; ++j)
                acc[j] = __builtin_amdgcn_mfma_f32_16x16x32_f16(af, bf[j], acc[j], 0, 0, 0);
            __builtin_amdgcn_s_setprio(0);
        }
    }

    // epilogue: C/D layout col=lane&15, row=quad*4+reg (HW-verified, dtype-indep)
    const bool doPool = (pooled != nullptr);
    if (doPool) {
        if (tid < 2 * BN) ((float*)spool)[tid] = 0.f;
        __syncthreads();
    }
    const int bA = row0 / HW_;                 // first batch this tile touches
    float ps[2][2] = {{0.f, 0.f}, {0.f, 0.f}}; // [batch-slot][j]
    float bcol[2];
    #pragma unroll
    for (int j = 0; j < 2; ++j) bcol[j] = bias[col0 + j * 16 + m15];
    #pragma unroll
    for (int r = 0; r < 4; ++r) {
        int row = row0 + wave * 16 + q * 4 + r;
        int slot = (row / HW_) - bA;           // 0 or 1 (64-row tile spans <= 2 batches)
        #pragma unroll
        for (int j = 0; j < 2; ++j) {
            int col = col0 + j * 16 + m15;
            float v = gelu_f(acc[j][r] + bcol[j]);
            out[(size_t)row * C_ + col] = (f16)v;
            if (doPool) ps[slot & 1][j] += v;
        }
    }
    if (doPool) {
        #pragma unroll
        for (int s = 0; s < 2; ++s)
            #pragma unroll
            for (int j = 0; j < 2; ++j)
                atomicAdd(&spool[s][j * 16 + m15], ps[s][j]);
        __syncthreads();
        if (tid < 2 * BN) {
            int slot = tid >> 5, colt = tid & 31;
            int b = bA + slot;
            int lastb = (row0 + BM - 1) / HW_;
            if (b <= lastb)                    // slot 1 only if tile spans batches
                atomicAdd(&pooled[(size_t)b * C_ + col0 + colt], spool[slot][colt]);
        }
    }
}

// ---------- gating MLP + softmax over anchors (pooled = raw column sums) ----------
// also re-zeroes its pooled row for the next target block (saves zero launches)
__global__ __launch_bounds__(256) void gate_kernel(float* __restrict__ pooled,
    const float* __restrict__ fc1w, const float* __restrict__ fc1b,
    const float* __restrict__ fc2w, const float* __restrict__ fc2b,
    int t, float* __restrict__ gates)
{
    __shared__ float sp[C_];
    __shared__ float sh2[2][HID_];
    __shared__ float sh[HID_];
    const int b = blockIdx.x, tid = threadIdx.x;

    float2 pv = *(const float2*)&pooled[b * C_ + 2 * tid];
    sp[2 * tid]     = pv.x * (1.f / 196.f);
    sp[2 * tid + 1] = pv.y * (1.f / 196.f);
    *(float2*)&pooled[b * C_ + 2 * tid] = make_float2(0.f, 0.f);  // ready for next target
    __syncthreads();

    // fc1: 2 threads per output (split C in halves), 256 iters each
    {
        int half = tid >> 7, hh = tid & 127;
        const float* w = fc1w + (size_t)t * C_ * HID_ + hh;
        float s = 0.f;
        int c0 = half * 256;
        for (int c = c0; c < c0 + 256; ++c) s += sp[c] * w[(size_t)c * HID_];
        sh2[half][hh] = s;
    }
    __syncthreads();
    if (tid < HID_) sh[tid] = gelu_f(sh2[0][tid] + sh2[1][tid] + fc1b[t * HID_ + tid]);
    __syncthreads();

    #pragma unroll
    for (int cc = 0; cc < 2; ++cc) {
        int c = tid + cc * 256;
        const float* w2 = fc2w + (size_t)t * HID_ * (3 * C_) + c;
        float l0 = fc2b[t * 3 * C_ + c];
        float l1 = fc2b[t * 3 * C_ + C_ + c];
        float l2 = fc2b[t * 3 * C_ + 2 * C_ + c];
        for (int j = 0; j < HID_; ++j) {
            float h = sh[j];
            const float* r = w2 + (size_t)j * 3 * C_;
            l0 += h * r[0];
            l1 += h * r[C_];
            l2 += h * r[2 * C_];
        }
        float m  = fmaxf(l0, fmaxf(l1, l2));
        float e0 = expf(l0 - m), e1 = expf(l1 - m), e2 = expf(l2 - m);
        float inv = 1.f / (e0 + e1 + e2);
        gates[(size_t)b * 3 * C_ + c]          = e0 * inv;
        gates[(size_t)b * 3 * C_ + C_ + c]     = e1 * inv;
        gates[(size_t)b * 3 * C_ + 2 * C_ + c] = e2 * inv;
    }
}

// ---------- nx += gamma * sum_a gates[b,a,c]*anchor_a ; t==2 also writes fp32 out ----------
// x8 vectorized: 16B f16 loads from 4 activation arrays (64 B/thread)
__global__ __launch_bounds__(256) void routed_add_kernel(f16* __restrict__ nx,
    const f16* __restrict__ a0, const f16* __restrict__ a1, const f16* __restrict__ a2,
    const float* __restrict__ gates, const float* __restrict__ gammas, int t,
    float* __restrict__ outf)
{
    int v = blockIdx.x * 256 + threadIdx.x;    // vector index (8 elems each)
    int idx = v * 8;
    int c = idx & (C_ - 1);
    int b = idx / (HW_ * C_);
    const float* g = gates + (size_t)b * 3 * C_ + c;
    float gamma = gammas[t];
    f16x8 xn = ((const f16x8*)nx)[v];
    f16x8 x0 = ((const f16x8*)a0)[v];
    f16x8 x1 = ((const f16x8*)a1)[v];
    f16x8 x2 = ((const f16x8*)a2)[v];
    float r[8];
    #pragma unroll
    for (int e = 0; e < 8; ++e)
        r[e] = (float)xn[e] + gamma * (g[e] * (float)x0[e] + g[C_ + e] * (float)x1[e]
                                       + g[2 * C_ + e] * (float)x2[e]);
    if (outf) {
        float4* o = (float4*)&outf[idx];
        o[0] = make_float4(r[0], r[1], r[2], r[3]);
        o[1] = make_float4(r[4], r[5], r[6], r[7]);
    } else {
        f16x8 o;
        #pragma unroll
        for (int e = 0; e < 8; ++e) o[e] = (f16)r[e];
        ((f16x8*)nx)[v] = o;
    }
}

extern "C" void kernel_launch(void* const* d_in, const int* in_sizes, int n_in,
                              void* d_out, int out_size, void* d_ws, size_t ws_size,
                              hipStream_t stream)
{
    const float* x      = (const float*)d_in[0];
    const float* blockw = (const float*)d_in[1];
    const float* blockb = (const float*)d_in[2];
    const float* fc1w   = (const float*)d_in[3];
    const float* fc1b   = (const float*)d_in[4];
    const float* fc2w   = (const float*)d_in[5];
    const float* fc2b   = (const float*)d_in[6];
    const float* gammas = (const float*)d_in[7];
    float* out = (float*)d_out;

    const size_t NB = (size_t)M_ * C_;            // 3,211,264 elems/activation
    f16* Wt = (f16*)d_ws;                          // 18*512*512 halfs = 9.44MB
    f16* P0 = Wt + (size_t)NBLK * C_ * C_;
    f16* P1 = P0 + NB;
    f16* A0 = P0 + 2 * NB;
    f16* A1 = P0 + 3 * NB;
    f16* A2 = P0 + 4 * NB;
    float* pooled = (float*)(P0 + 5 * NB);         // 32*512 fp32 raw column sums
    float* gates  = pooled + B_ * C_;

    conv_w<<<dim3(8, 8, NBLK), 256, 0, stream>>>(blockw, Wt);
    conv_x<<<(int)(NB / 1024), 256, 0, stream>>>(x, P1, pooled);

    // x(fp16)=P1 feeds block 0; anchors (blocks 1,4,9 outputs) pinned A0/A1/A2
    const f16* ins[NBLK]  = {P1, P0, A0, P0, P1, A1, P0, P1, P0, P1, A2, P0, P1, P0, P1, P0, P1, P0};
    f16*       outs[NBLK] = {P0, A0, P0, P1, A1, P0, P1, P0, P1, A2, P0, P1, P0, P1, P0, P1, P0, P1};

    for (int i = 0; i < NBLK; ++i) {
        int t = (i == 11) ? 0 : (i == 14) ? 1 : (i == 17) ? 2 : -1;
        gemm_f16<<<dim3(M_ / BM, C_ / BN), 256, 0, stream>>>(
            ins[i], Wt, blockb, i, outs[i], (t >= 0) ? pooled : (float*)nullptr);
        if (t >= 0) {
            gate_kernel<<<B_, 256, 0, stream>>>(pooled, fc1w, fc1b, fc2w, fc2b, t, gates);
            routed_add_kernel<<<(int)(NB / 2048), 256, 0, stream>>>(
                outs[i], A0, A1, A2, gates, gammas, t,
                (t == 2) ? out : (float*)nullptr);
        }
    }
}

// Round 10
// 395.357 us; speedup vs baseline: 1.1290x; 1.1290x over previous
//
#include <hip/hip_runtime.h>

#define B_   32
#define HW_  196
#define C_   512
#define M_   (B_*HW_)    // 6272
#define HID_ 128
#define NBLK 18

typedef _Float16 f16;
typedef _Float16 f16x2 __attribute__((ext_vector_type(2)));
typedef _Float16 f16x4 __attribute__((ext_vector_type(4)));
typedef _Float16 f16x8 __attribute__((ext_vector_type(8)));
typedef float    f32x4 __attribute__((ext_vector_type(4)));

__device__ __forceinline__ float gelu_f(float x) {
    float t = tanhf(0.7978845608028654f * (x + 0.044715f * x * x * x));
    return 0.5f * x * (1.0f + t);
}

// async global->LDS, 16B per lane; LDS dest = wave-uniform base + lane*16
__device__ __forceinline__ void gl16(const void* g, void* l) {
    __builtin_amdgcn_global_load_lds((const __attribute__((address_space(1))) unsigned*)g,
                                     (__attribute__((address_space(3))) unsigned*)l, 16, 0, 0);
}

// ---------- weights: fp32 [blk][k][n] -> fp16 transposed [blk][n][k] ----------
__global__ __launch_bounds__(256) void conv_w(const float* __restrict__ W,
                                              f16* __restrict__ Wt) {
    __shared__ f16 sh[64][72];
    const int blk = blockIdx.z, k0 = blockIdx.x * 64, n0 = blockIdx.y * 64;
    const int tid = threadIdx.x;
    const float* Wb = W + (size_t)blk * C_ * C_;
    #pragma unroll
    for (int i = 0; i < 4; ++i) {
        int s = tid + i * 256, r = s >> 4, c4 = (s & 15) << 2;
        float4 v = *(const float4*)&Wb[(size_t)(k0 + r) * C_ + n0 + c4];
        sh[r][c4 + 0] = (f16)v.x; sh[r][c4 + 1] = (f16)v.y;
        sh[r][c4 + 2] = (f16)v.z; sh[r][c4 + 3] = (f16)v.w;
    }
    __syncthreads();
    #pragma unroll
    for (int i = 0; i < 2; ++i) {
        int s = tid + i * 256, r = s >> 3, c8 = (s & 7) << 3;
        f16x8 o;
        #pragma unroll
        for (int j = 0; j < 8; ++j) o[j] = sh[c8 + j][r];
        *(f16x8*)&Wt[(size_t)blk * C_ * C_ + (size_t)(n0 + r) * C_ + k0 + c8] = o;
    }
}

// ---------- x: fp32 -> fp16 (x4 vectorized); first 64 blocks also zero pooled ----------
__global__ __launch_bounds__(256) void conv_x(const float* __restrict__ in,
                                              f16* __restrict__ out,
                                              float* __restrict__ pooled) {
    int i = blockIdx.x * 256 + threadIdx.x;
    if (blockIdx.x < 64) pooled[i] = 0.f;   // 64*256 = 16384 = B_*C_
    float4 a = ((const float4*)in)[i];
    f16x4 o; o[0] = (f16)a.x; o[1] = (f16)a.y; o[2] = (f16)a.z; o[3] = (f16)a.w;
    ((f16x4*)out)[i] = o;
}

// ---------- MFMA GEMM: out = gelu(A[M,K]@W_blk[K,N] + b) [+ column-sum pooling] ----------
// 64x64 tile, 4 waves (2x2 grid of 32x32). ONE change vs r6 (385us): the K-loop.
// Model (r6/r8/r9): staging is HBM-LATENCY/duty-cycle bound — drain loop idles each
// chain between 16KB bursts (effective BW 4.0/5.7/7.3 TB/s scaling with chain count).
// Fix: BK=32, 4 LDS buffers (32KB total — SAME footprint/occupancy as r6, 784
// all-resident), 3-deep prefetch, counted vmcnt (never drains mid-loop) -> loads
// continuously outstanding (24KB/block) -> duty ~100%.
// LDS swizzle for BK=32 (row stride 64B = half bank wrap): col-block c^((r>>1)&3)
// -> rows 0..7 hit 8 distinct bank slots, 16 rows = 2-way = free (m136).
// Source pre-swizzle: lane l -> row l>>2, src col-block (l&3)^((l>>3)&3).
#define BM 64
#define BN 64
#define BK 32
#define NKT (C_ / BK)   // 16
__global__ __launch_bounds__(256, 4) void gemm_f16(
    const f16* __restrict__ A, const f16* __restrict__ Wt,
    const float* __restrict__ ball, int blk, f16* __restrict__ out,
    float* __restrict__ pooled)
{
    __shared__ f16 As[4][BM * BK];   // 4 x 4 KB
    __shared__ f16 Ws[4][BN * BK];   // 4 x 4 KB  -> 32 KB total, 4 blocks/CU
    __shared__ float spool[2][BN];   // per-batch-slot column sums (512 B)
    const int tid = threadIdx.x;
    const int wave = tid >> 6, lane = tid & 63;
    const int m15 = lane & 15, q = lane >> 4;
    const int wr = wave >> 1, wc = wave & 1;           // 2x2 wave grid, 32x32 tiles

    // chunked-XCD swizzle (bijective, 784 = 8*98) — unchanged from r6
    const int lin  = blockIdx.x + 98 * blockIdx.y;     // hw dispatch order
    const int tile = (lin & 7) * 98 + (lin >> 3);      // contiguous chunk per XCD
    const int rb   = tile >> 3, cb = tile & 7;
    const int row0 = rb * BM, col0 = cb * BN;

    const f16* Wb = Wt + (size_t)blk * C_ * C_;
    const float* bias = ball + (size_t)blk * C_;

    // staging: per K-step each wave issues 1 A-chunk + 1 W-chunk (1KB each,
    // 16 rows x 32 halfs). lane l -> row chunk*16+(l>>2), src col-block
    // (l&3)^((l>>3)&3) (pre-swizzled so linear LDS = swizzled layout).
    const int srow = lane >> 2;                         // 0..15
    const int scol = ((lane & 3) ^ ((lane >> 3) & 3)) << 3;   // halfs
    const f16* aSrc = A  + (size_t)(row0 + wave * 16 + srow) * C_ + scol;
    const f16* wSrc = Wb + (size_t)(col0 + wave * 16 + srow) * C_ + scol;
    f16* aDst[4]; f16* wDst[4];
    #pragma unroll
    for (int bb = 0; bb < 4; ++bb) {
        aDst[bb] = &As[bb][wave * 512];                 // 512 halfs = 16 rows x 32
        wDst[bb] = &Ws[bb][wave * 512];
    }

    f32x4 acc[2][2];
    #pragma unroll
    for (int i = 0; i < 2; ++i)
        #pragma unroll
        for (int j = 0; j < 2; ++j) acc[i][j] = (f32x4)0.f;

    // prologue: prefetch K-steps 0,1,2 (2 gl16 each -> 6 outstanding/wave)
    #pragma unroll
    for (int t = 0; t < 3; ++t) {
        gl16(aSrc + t * BK, aDst[t]);
        gl16(wSrc + t * BK, wDst[t]);
    }

    #pragma unroll
    for (int kt = 0; kt < NKT; ++kt) {
        // wait for step kt's 2 loads only (6 outstanding in steady state)
        if (kt <= NKT - 3)      asm volatile("s_waitcnt vmcnt(4)" ::: "memory");
        else if (kt == NKT - 2) asm volatile("s_waitcnt vmcnt(2)" ::: "memory");
        else                    asm volatile("s_waitcnt vmcnt(0)" ::: "memory");
        asm volatile("s_barrier" ::: "memory");   // all waves' kt loads landed
        __builtin_amdgcn_sched_barrier(0);

        // issue kt+3 into buf (kt+3)&3 = buf of tile kt-1, whose reads all
        // waves finished before the barrier above.
        if (kt + 3 < NKT) {
            const int nb = (kt + 3) & 3, koff = (kt + 3) * BK;
            gl16(aSrc + koff, aDst[nb]);
            gl16(wSrc + koff, wDst[nb]);
        }

        const f16* Ab = &As[kt & 3][0];
        const f16* Bb = &Ws[kt & 3][0];
        f16x8 af[2], bf[2];
        #pragma unroll
        for (int i = 0; i < 2; ++i) {
            int r = wr * 32 + i * 16 + m15;
            af[i] = *(const f16x8*)&Ab[r * 32 + ((q ^ ((r >> 1) & 3)) << 3)];
        }
        #pragma unroll
        for (int j = 0; j < 2; ++j) {
            int r = wc * 32 + j * 16 + m15;
            bf[j] = *(const f16x8*)&Bb[r * 32 + ((q ^ ((r >> 1) & 3)) << 3)];
        }
        __builtin_amdgcn_s_setprio(1);
        #pragma unroll
        for (int i = 0; i < 2; ++i)
            #pragma unroll
            for (int j = 0; j < 2; ++j)
                acc[i][j] = __builtin_amdgcn_mfma_f32_16x16x32_f16(af[i], bf[j], acc[i][j], 0, 0, 0);
        __builtin_amdgcn_s_setprio(0);
    }

    // epilogue: C/D layout col=lane&15, row=quad*4+reg (HW-verified, dtype-indep)
    const bool doPool = (pooled != nullptr);
    if (doPool) {
        if (tid < 2 * BN) ((float*)spool)[tid] = 0.f;
        __syncthreads();
    }
    const int bA = row0 / HW_;                 // first batch this tile touches
    float ps[2][2] = {{0.f, 0.f}, {0.f, 0.f}}; // [batch-slot][j] partial sums
    float bcol[2];
    #pragma unroll
    for (int j = 0; j < 2; ++j) bcol[j] = bias[col0 + wc * 32 + j * 16 + m15];
    #pragma unroll
    for (int i = 0; i < 2; ++i) {
        #pragma unroll
        for (int r = 0; r < 4; ++r) {
            int rloc = wr * 32 + i * 16 + q * 4 + r;
            int row = row0 + rloc;
            int slot = (row / HW_) - bA;       // 0 or 1 (tile spans <= 2 batches)
            #pragma unroll
            for (int j = 0; j < 2; ++j) {
                int col = col0 + wc * 32 + j * 16 + m15;
                float v = gelu_f(acc[i][j][r] + bcol[j]);
                out[(size_t)row * C_ + col] = (f16)v;
                if (doPool) ps[slot & 1][j] += v;
            }
        }
    }
    if (doPool) {
        #pragma unroll
        for (int s = 0; s < 2; ++s)
            #pragma unroll
            for (int j = 0; j < 2; ++j)
                atomicAdd(&spool[s][wc * 32 + j * 16 + m15], ps[s][j]);
        __syncthreads();
        if (tid < 2 * BN) {
            int slot = tid >> 6, colt = tid & 63;
            int b = bA + slot;
            int lastb = (row0 + BM - 1) / HW_;
            if (b <= lastb)                    // slot 1 only if tile spans batches
                atomicAdd(&pooled[(size_t)b * C_ + col0 + colt], spool[slot][colt]);
        }
    }
}

// ---------- gating MLP + softmax over anchors (pooled = raw column sums) ----------
// also re-zeroes its pooled row for the next target block (saves zero launches)
__global__ __launch_bounds__(256) void gate_kernel(float* __restrict__ pooled,
    const float* __restrict__ fc1w, const float* __restrict__ fc1b,
    const float* __restrict__ fc2w, const float* __restrict__ fc2b,
    int t, float* __restrict__ gates)
{
    __shared__ float sp[C_];
    __shared__ float sh2[2][HID_];
    __shared__ float sh[HID_];
    const int b = blockIdx.x, tid = threadIdx.x;

    float2 pv = *(const float2*)&pooled[b * C_ + 2 * tid];
    sp[2 * tid]     = pv.x * (1.f / 196.f);
    sp[2 * tid + 1] = pv.y * (1.f / 196.f);
    *(float2*)&pooled[b * C_ + 2 * tid] = make_float2(0.f, 0.f);  // ready for next target
    __syncthreads();

    // fc1: 2 threads per output (split C in halves), 256 iters each
    {
        int half = tid >> 7, hh = tid & 127;
        const float* w = fc1w + (size_t)t * C_ * HID_ + hh;
        float s = 0.f;
        int c0 = half * 256;
        for (int c = c0; c < c0 + 256; ++c) s += sp[c] * w[(size_t)c * HID_];
        sh2[half][hh] = s;
    }
    __syncthreads();
    if (tid < HID_) sh[tid] = gelu_f(sh2[0][tid] + sh2[1][tid] + fc1b[t * HID_ + tid]);
    __syncthreads();

    #pragma unroll
    for (int cc = 0; cc < 2; ++cc) {
        int c = tid + cc * 256;
        const float* w2 = fc2w + (size_t)t * HID_ * (3 * C_) + c;
        float l0 = fc2b[t * 3 * C_ + c];
        float l1 = fc2b[t * 3 * C_ + C_ + c];
        float l2 = fc2b[t * 3 * C_ + 2 * C_ + c];
        for (int j = 0; j < HID_; ++j) {
            float h = sh[j];
            const float* r = w2 + (size_t)j * 3 * C_;
            l0 += h * r[0];
            l1 += h * r[C_];
            l2 += h * r[2 * C_];
        }
        float m  = fmaxf(l0, fmaxf(l1, l2));
        float e0 = expf(l0 - m), e1 = expf(l1 - m), e2 = expf(l2 - m);
        float inv = 1.f / (e0 + e1 + e2);
        gates[(size_t)b * 3 * C_ + c]          = e0 * inv;
        gates[(size_t)b * 3 * C_ + C_ + c]     = e1 * inv;
        gates[(size_t)b * 3 * C_ + 2 * C_ + c] = e2 * inv;
    }
}

// ---------- nx += gamma * sum_a gates[b,a,c]*anchor_a ; t==2 also writes fp32 out ----------
// x8 vectorized: 16B f16 loads from 4 activation arrays (64 B/thread)
__global__ __launch_bounds__(256) void routed_add_kernel(f16* __restrict__ nx,
    const f16* __restrict__ a0, const f16* __restrict__ a1, const f16* __restrict__ a2,
    const float* __restrict__ gates, const float* __restrict__ gammas, int t,
    float* __restrict__ outf)
{
    int v = blockIdx.x * 256 + threadIdx.x;    // vector index (8 elems each)
    int idx = v * 8;
    int c = idx & (C_ - 1);
    int b = idx / (HW_ * C_);
    const float* g = gates + (size_t)b * 3 * C_ + c;
    float gamma = gammas[t];
    f16x8 xn = ((const f16x8*)nx)[v];
    f16x8 x0 = ((const f16x8*)a0)[v];
    f16x8 x1 = ((const f16x8*)a1)[v];
    f16x8 x2 = ((const f16x8*)a2)[v];
    float r[8];
    #pragma unroll
    for (int e = 0; e < 8; ++e)
        r[e] = (float)xn[e] + gamma * (g[e] * (float)x0[e] + g[C_ + e] * (float)x1[e]
                                       + g[2 * C_ + e] * (float)x2[e]);
    if (outf) {
        float4* o = (float4*)&outf[idx];
        o[0] = make_float4(r[0], r[1], r[2], r[3]);
        o[1] = make_float4(r[4], r[5], r[6], r[7]);
    } else {
        f16x8 o;
        #pragma unroll
        for (int e = 0; e < 8; ++e) o[e] = (f16)r[e];
        ((f16x8*)nx)[v] = o;
    }
}

extern "C" void kernel_launch(void* const* d_in, const int* in_sizes, int n_in,
                              void* d_out, int out_size, void* d_ws, size_t ws_size,
                              hipStream_t stream)
{
    const float* x      = (const float*)d_in[0];
    const float* blockw = (const float*)d_in[1];
    const float* blockb = (const float*)d_in[2];
    const float* fc1w   = (const float*)d_in[3];
    const float* fc1b   = (const float*)d_in[4];
    const float* fc2w   = (const float*)d_in[5];
    const float* fc2b   = (const float*)d_in[6];
    const float* gammas = (const float*)d_in[7];
    float* out = (float*)d_out;

    const size_t NB = (size_t)M_ * C_;            // 3,211,264 elems/activation
    f16* Wt = (f16*)d_ws;                          // 18*512*512 halfs = 9.44MB
    f16* P0 = Wt + (size_t)NBLK * C_ * C_;
    f16* P1 = P0 + NB;
    f16* A0 = P0 + 2 * NB;
    f16* A1 = P0 + 3 * NB;
    f16* A2 = P0 + 4 * NB;
    float* pooled = (float*)(P0 + 5 * NB);         // 32*512 fp32 raw column sums
    float* gates  = pooled + B_ * C_;

    conv_w<<<dim3(8, 8, NBLK), 256, 0, stream>>>(blockw, Wt);
    conv_x<<<(int)(NB / 1024), 256, 0, stream>>>(x, P1, pooled);

    // x(fp16)=P1 feeds block 0; anchors (blocks 1,4,9 outputs) pinned A0/A1/A2
    const f16* ins[NBLK]  = {P1, P0, A0, P0, P1, A1, P0, P1, P0, P1, A2, P0, P1, P0, P1, P0, P1, P0};
    f16*       outs[NBLK] = {P0, A0, P0, P1, A1, P0, P1, P0, P1, A2, P0, P1, P0, P1, P0, P1, P0, P1};

    for (int i = 0; i < NBLK; ++i) {
        int t = (i == 11) ? 0 : (i == 14) ? 1 : (i == 17) ? 2 : -1;
        gemm_f16<<<dim3(M_ / BM, C_ / BN), 256, 0, stream>>>(
            ins[i], Wt, blockb, i, outs[i], (t >= 0) ? pooled : (float*)nullptr);
        if (t >= 0) {
            gate_kernel<<<B_, 256, 0, stream>>>(pooled, fc1w, fc1b, fc2w, fc2b, t, gates);
            routed_add_kernel<<<(int)(NB / 2048), 256, 0, stream>>>(
                outs[i], A0, A1, A2, gates, gammas, t,
                (t == 2) ? out : (float*)nullptr);
        }
    }
}